// Round 12
// baseline (598.825 us; speedup 1.0000x reference)
//
#include <hip/hip_runtime.h>

#define AS1 __attribute__((address_space(1)))
#define AS3 __attribute__((address_space(3)))

typedef unsigned short u16;
typedef unsigned int u32;
typedef __attribute__((ext_vector_type(8))) __bf16 bf16x8;
typedef __attribute__((ext_vector_type(8))) unsigned short u16x8;
typedef __attribute__((ext_vector_type(4))) float f32x4;

// Problem constants
#define BATCH   4
#define SEQLEN  2048
#define DMODEL  1024
#define DINNER  2048
#define DSTATE  16
#define ROWS    (BATCH * SEQLEN)   // 8192

__device__ __forceinline__ u16 f2bf(float f) {
  union { float f; unsigned u; } v; v.f = f;
  unsigned u = v.u;
  return (u16)((u + 0x7fffu + ((u >> 16) & 1u)) >> 16);   // RNE
}
__device__ __forceinline__ float bf2f(u16 s) {
  union { unsigned u; float f; } v; v.u = ((unsigned)s) << 16;
  return v.f;
}
__device__ __forceinline__ float bflo(u32 p) { union { unsigned u; float f; } v; v.u = p << 16; return v.f; }
__device__ __forceinline__ float bfhi(u32 p) { union { unsigned u; float f; } v; v.u = p & 0xffff0000u; return v.f; }

// asm ds_read_b128 with compile-time offset; address is a 32-bit LDS byte address.
template<int IMM>
__device__ __forceinline__ bf16x8 dsr(unsigned addr) {
  bf16x8 r;
  asm volatile("ds_read_b128 %0, %1 offset:%2" : "=&v"(r) : "v"(addr), "i"(IMM));
  return r;
}
__device__ __forceinline__ unsigned lds_addr(const u16* p) {
  return (unsigned)(size_t)(const AS3 u16*)p;
}
template<int N>
__device__ __forceinline__ void lgkm() {
  asm volatile("s_waitcnt lgkmcnt(%0)" :: "i"(N) : "memory");
  __builtin_amdgcn_sched_barrier(0);   // rule #18
}

// ---------------- cast f32 -> bf16 (4 elems/thread) ----------------
__global__ void cast_f32_bf16(const float* __restrict__ in, u16* __restrict__ out, int n4) {
  int i = blockIdx.x * blockDim.x + threadIdx.x;
  if (i >= n4) return;
  float4 v = ((const float4*)in)[i];
  ushort4 o;
  o.x = f2bf(v.x); o.y = f2bf(v.y); o.z = f2bf(v.z); o.w = f2bf(v.w);
  ((ushort4*)out)[i] = o;
}

// ---------------- transpose + cast: in f32 (R x C) -> out bf16 (C x R) ----------------
__global__ void transpose_cast(const float* __restrict__ in, u16* __restrict__ out, int R, int C) {
  __shared__ float tile[32][33];
  int x  = blockIdx.x * 32 + threadIdx.x;
  int y0 = blockIdx.y * 32;
#pragma unroll
  for (int j = 0; j < 32; j += 8)
    tile[threadIdx.y + j][threadIdx.x] = in[(size_t)(y0 + threadIdx.y + j) * C + x];
  __syncthreads();
  int xo  = blockIdx.y * 32 + threadIdx.x;
  int yo0 = blockIdx.x * 32;
#pragma unroll
  for (int j = 0; j < 32; j += 8)
    out[(size_t)(yo0 + threadIdx.y + j) * R + xo] = f2bf(tile[threadIdx.x][threadIdx.y + j]);
}

// ---------------- 256xBN bf16 MFMA GEMM — merged phase: ONE barrier per K-tile ----------------
// Per K-tile: stage next tile (8 global_load_lds) -> 24 ds_read_b128 (kk0 then kk1)
// -> lgkm(12) -> 32 MFMA (kk0) -> lgkm(0) -> 32 MFMA (kk1) -> vmcnt(0) -> s_barrier.
// T2 swizzle (0 conflicts), 2D XCD supertiles, 512 thr = 8 waves (2M x 4N), BK=64.
// EPI: 0 = store bf16, 1 = softplus(v + bias[col]) -> bf16, 2 = store f32
template<int EPI, int BN_>
__launch_bounds__(512, 1)
__global__ void gemm8p(const u16* __restrict__ A, const u16* __restrict__ Bt,
                       void* __restrict__ outp, const float* __restrict__ bias,
                       int M, int N, int K, int gn, int rr, int cc) {
  constexpr int NF   = BN_ / 64;
  constexpr int BCH  = BN_ / 64;
  constexpr int ASZ  = 256 * 64;
  constexpr int BSZ  = BN_ * 64;
  constexpr int BUFS = ASZ + BSZ;
  extern __shared__ u16 lds[];

  const int xcd = blockIdx.x & 7, kb = blockIdx.x >> 3;
  const int tpr = gn / cc;
  const int bm  = (xcd / tpr) * rr + kb / cc;
  const int bn  = (xcd % tpr) * cc + kb % cc;

  const int tid  = threadIdx.x;
  const int wave = tid >> 6, lane = tid & 63;
  const int wm = wave >> 2, wn = wave & 3;
  const int llo = lane & 15, lhi = lane >> 4;
  const size_t bm0 = (size_t)bm * 256, bn0 = (size_t)bn * BN_;
  const int NT = K >> 6;

  const u16* gA[4];
#pragma unroll
  for (int ch = 0; ch < 4; ++ch) {
    int row  = ch * 64 + (tid >> 3);
    int scol = ((tid & 7) ^ (row & 7)) << 3;
    gA[ch] = A + (bm0 + row) * (size_t)K + scol;
  }
  const u16* gB[BCH];
#pragma unroll
  for (int ch = 0; ch < BCH; ++ch) {
    int row  = ch * 64 + (tid >> 3);
    int scol = ((tid & 7) ^ (row & 7)) << 3;
    gB[ch] = Bt + (bn0 + row) * (size_t)K + scol;
  }

  unsigned aA[2][2], aB[2][2];
  {
    const unsigned base0 = lds_addr(lds);
    const unsigned rowA = (unsigned)(wm * 128 + llo) * 128u;
    const unsigned rowB = (unsigned)(wn * (NF * 16) + llo) * 128u;
    const unsigned msk = (unsigned)((llo & 7) << 4);
#pragma unroll
    for (int bf = 0; bf < 2; ++bf)
#pragma unroll
      for (int kk = 0; kk < 2; ++kk) {
        unsigned colk = ((unsigned)(kk * 64 + lhi * 16)) ^ msk;
        aA[bf][kk] = base0 + (unsigned)bf * (BUFS * 2) + rowA + colk;
        aB[bf][kk] = base0 + (unsigned)bf * (BUFS * 2) + (ASZ * 2) + rowB + colk;
      }
  }

#define SGA(t, bsel, ch) __builtin_amdgcn_global_load_lds(                       \
    (const AS1 void*)(gA[ch] + ((size_t)(t) << 6)),                              \
    (AS3 void*)(lds + (bsel) * BUFS + (ch) * 4096 + wave * 512), 16, 0, 0)
#define SGB(t, bsel, ch) __builtin_amdgcn_global_load_lds(                       \
    (const AS1 void*)(gB[ch] + ((size_t)(t) << 6)),                              \
    (AS3 void*)(lds + (bsel) * BUFS + ASZ + (ch) * 4096 + wave * 512), 16, 0, 0)

  f32x4 acc[8][NF] = {};

#define MM(AV, BV)                                                               \
    __builtin_amdgcn_s_setprio(1);                                               \
    _Pragma("unroll") for (int mh = 0; mh < 2; ++mh)                             \
      _Pragma("unroll") for (int m = 0; m < 4; ++m)                              \
        _Pragma("unroll") for (int n = 0; n < NF; ++n)                           \
          acc[mh * 4 + m][n] = __builtin_amdgcn_mfma_f32_16x16x32_bf16(          \
              AV[mh * 4 + m], BV[n], acc[mh * 4 + m][n], 0, 0, 0);               \
    __builtin_amdgcn_s_setprio(0);

#define KTILE(BUF, DOSTG, TNEXT)                                                 \
  {                                                                              \
    if (DOSTG) {                                                                 \
      SGA(TNEXT, (BUF) ^ 1, 0); SGA(TNEXT, (BUF) ^ 1, 1);                        \
      SGA(TNEXT, (BUF) ^ 1, 2); SGA(TNEXT, (BUF) ^ 1, 3);                        \
      SGB(TNEXT, (BUF) ^ 1, 0); SGB(TNEXT, (BUF) ^ 1, 1);                        \
      if (BCH == 4) { SGB(TNEXT, (BUF) ^ 1, 2); SGB(TNEXT, (BUF) ^ 1, 3); }      \
    }                                                                            \
    bf16x8 a0[8], a1[8], b0[NF], b1[NF];                                         \
    a0[0] = dsr<0>(aA[BUF][0]);     a0[1] = dsr<2048>(aA[BUF][0]);               \
    a0[2] = dsr<4096>(aA[BUF][0]);  a0[3] = dsr<6144>(aA[BUF][0]);               \
    a0[4] = dsr<8192>(aA[BUF][0]);  a0[5] = dsr<10240>(aA[BUF][0]);              \
    a0[6] = dsr<12288>(aA[BUF][0]); a0[7] = dsr<14336>(aA[BUF][0]);              \
    b0[0] = dsr<0>(aB[BUF][0]);     b0[1] = dsr<2048>(aB[BUF][0]);               \
    if constexpr (NF == 4) {                                                     \
      b0[2] = dsr<4096>(aB[BUF][0]); b0[3] = dsr<6144>(aB[BUF][0]);              \
    }                                                                            \
    a1[0] = dsr<0>(aA[BUF][1]);     a1[1] = dsr<2048>(aA[BUF][1]);               \
    a1[2] = dsr<4096>(aA[BUF][1]);  a1[3] = dsr<6144>(aA[BUF][1]);               \
    a1[4] = dsr<8192>(aA[BUF][1]);  a1[5] = dsr<10240>(aA[BUF][1]);              \
    a1[6] = dsr<12288>(aA[BUF][1]); a1[7] = dsr<14336>(aA[BUF][1]);              \
    b1[0] = dsr<0>(aB[BUF][1]);     b1[1] = dsr<2048>(aB[BUF][1]);               \
    if constexpr (NF == 4) {                                                     \
      b1[2] = dsr<4096>(aB[BUF][1]); b1[3] = dsr<6144>(aB[BUF][1]);              \
    }                                                                            \
    lgkm<8 + NF>();   /* kk0 group landed; kk1 drains under MFMA */              \
    MM(a0, b0);                                                                  \
    lgkm<0>();                                                                   \
    MM(a1, b1);                                                                  \
    asm volatile("s_waitcnt vmcnt(0)" ::: "memory");                             \
    asm volatile("s_barrier" ::: "memory");                                      \
  }

  // prologue: tile 0 -> buf 0
  SGA(0, 0, 0); SGA(0, 0, 1); SGA(0, 0, 2); SGA(0, 0, 3);
  SGB(0, 0, 0); SGB(0, 0, 1);
  if (BCH == 4) { SGB(0, 0, 2); SGB(0, 0, 3); }
  asm volatile("s_waitcnt vmcnt(0)" ::: "memory");
  asm volatile("s_barrier" ::: "memory");

  for (int u = 0; u < NT; u += 2) {
    KTILE(0, true, u + 1);                 // tile u from buf0; stage u+1 -> buf1
    KTILE(1, (u + 2) < NT, u + 2);         // tile u+1 from buf1; stage u+2 -> buf0
  }
#undef KTILE
#undef MM
#undef SGA
#undef SGB

  // epilogue: C mapping col = n*16+llo, row = 16*frag + lhi*4 + r
#pragma unroll
  for (int am = 0; am < 8; ++am) {
    const int mh = am >> 2, m = am & 3;
    const int rowb = (int)bm0 + wm * 128 + mh * 64 + m * 16 + lhi * 4;
#pragma unroll
    for (int n = 0; n < NF; ++n) {
      const int col = (int)bn0 + wn * (16 * NF) + n * 16 + llo;
#pragma unroll
      for (int r = 0; r < 4; ++r) {
        float v = acc[am][n][r];
        size_t idx = (size_t)(rowb + r) * N + col;
        if (EPI == 0) {
          ((u16*)outp)[idx] = f2bf(v);
        } else if (EPI == 1) {
          float xb = v + bias[col];
          float sp = (xb > 20.f) ? xb : log1pf(__expf(xb));  // softplus
          ((u16*)outp)[idx] = f2bf(sp);
        } else {
          ((float*)outp)[idx] = v;
        }
      }
    }
  }
}

// ---------------- causal depthwise conv (K=4) + SiLU, 4 d per thread ----------------
__global__ void conv_silu4(const u16* __restrict__ xz, const float* __restrict__ w,
                           const float* __restrict__ cb, u16* __restrict__ xs, int total4) {
  int idx = blockIdx.x * 256 + threadIdx.x;
  if (idx >= total4) return;
  int d4 = idx & (DINNER / 4 - 1);
  int l  = (idx >> 9) & (SEQLEN - 1);
  int b  = idx >> 20;
  int d  = d4 * 4;
  float4 wv[4];
#pragma unroll
  for (int j = 0; j < 4; ++j) wv[j] = ((const float4*)w)[d + j];
  float4 bias = *(const float4*)(cb + d);
  float acc[4] = { bias.x, bias.y, bias.z, bias.w };
#pragma unroll
  for (int k = 0; k < 4; ++k) {
    int li = l - 3 + k;
    if (li >= 0) {
      ushort4 xv = *(const ushort4*)(xz + (size_t)(b * SEQLEN + li) * (2 * DINNER) + d);
      acc[0] = fmaf((&wv[0].x)[k], bf2f(xv.x), acc[0]);
      acc[1] = fmaf((&wv[1].x)[k], bf2f(xv.y), acc[1]);
      acc[2] = fmaf((&wv[2].x)[k], bf2f(xv.z), acc[2]);
      acc[3] = fmaf((&wv[3].x)[k], bf2f(xv.w), acc[3]);
    }
  }
  ushort4 o;
  o.x = f2bf(acc[0] / (1.f + __expf(-acc[0])));
  o.y = f2bf(acc[1] / (1.f + __expf(-acc[1])));
  o.z = f2bf(acc[2] / (1.f + __expf(-acc[2])));
  o.w = f2bf(acc[3] / (1.f + __expf(-acc[3])));
  *(ushort4*)(xs + (size_t)idx * 4) = o;
}

// ---------------- x-projection: xproj(ROWS x 32) = xs(ROWS x 2048) @ Wx(2048 x 32) ----------------
__global__ void xproj_kernel(const u16* __restrict__ xs, const float* __restrict__ Wx,
                             float* __restrict__ outp) {
  __shared__ float part[256];
  int row = blockIdx.x;
  int tid = threadIdx.x;
  int c = tid & 31, kp = tid >> 5;
  const u16* xr = xs + (size_t)row * DINNER + kp * 256;
  const float* wp = Wx + (size_t)(kp * 256) * 32 + c;
  float acc = 0.f;
#pragma unroll 4
  for (int kk = 0; kk < 32; ++kk) {
    u16x8 xv = *(const u16x8*)(const void*)(xr + kk * 8);
#pragma unroll
    for (int j = 0; j < 8; ++j)
      acc = fmaf(bf2f(xv[j]), wp[(kk * 8 + j) * 32], acc);
  }
  part[tid] = acc;
  __syncthreads();
  if (tid < 32) {
    float s = 0.f;
#pragma unroll
    for (int p = 0; p < 8; ++p) s += part[p * 32 + tid];
    outp[(size_t)row * 32 + tid] = s;
  }
}

// ---------------- chunked selective scan v3 (R6 version — best measured) ----------------
#define SC_NC 32                // chunks
#define SC_CL 64                // steps per chunk
#define SC_LDS (2 * SC_NC * 16 * 33 * 4)   // 135168 B

__launch_bounds__(512, 1)
__global__ void scan_v3(const u16* __restrict__ delta, const u16* __restrict__ xs,
                        const float* __restrict__ xproj, const u16* __restrict__ xz,
                        const float* __restrict__ A_log, const float* __restrict__ Dp,
                        u16* __restrict__ yg) {
  extern __shared__ float smem[];
  float* cP = smem;
  float* cH = smem + SC_NC * 16 * 33;
  const int tid = threadIdx.x;
  const int dl = tid & 15, ck = tid >> 4;
  const int b = blockIdx.x >> 6, dblk = blockIdx.x & 63;
  const int d0 = dblk * 32 + dl * 2;
  const int r0 = b * SEQLEN + ck * SC_CL;

  float A0[DSTATE], A1[DSTATE];
  {
    const f32x4* ap0 = (const f32x4*)(A_log + (size_t)d0 * DSTATE);
    const f32x4* ap1 = (const f32x4*)(A_log + (size_t)(d0 + 1) * DSTATE);
#pragma unroll
    for (int q = 0; q < 4; ++q) {
      f32x4 a0 = ap0[q], a1 = ap1[q];
#pragma unroll
      for (int j = 0; j < 4; ++j) { A0[q * 4 + j] = -__expf(a0[j]); A1[q * 4 + j] = -__expf(a1[j]); }
    }
  }

  const u32* dP = (const u32*)(delta + (size_t)r0 * DINNER + d0);
  const u32* xP = (const u32*)(xs    + (size_t)r0 * DINNER + d0);
  const u32* zP = (const u32*)(xz + (size_t)r0 * (2 * DINNER) + DINNER + d0);
  const float* bP = xproj + (size_t)r0 * 32;
  const int DW = DINNER / 2;
  const int ZW = DINNER;

  float P0[DSTATE], P1[DSTATE], H0[DSTATE], H1[DSTATE];
#pragma unroll
  for (int s = 0; s < DSTATE; ++s) { P0[s] = P1[s] = 1.f; H0[s] = H1[s] = 0.f; }
  {
    u32 dq0 = dP[0], xq0 = xP[0];
    u32 dq1 = dP[DW], xq1 = xP[DW];
    f32x4 Bn[4];
#pragma unroll
    for (int q = 0; q < 4; ++q) Bn[q] = ((const f32x4*)bP)[q];
    for (int l = 0; l < SC_CL; ++l) {
      const u32 dc = dq0, xc = xq0;
      dq0 = dq1; xq0 = xq1;
      if (l + 2 < SC_CL) { dq1 = dP[(l + 2) * DW]; xq1 = xP[(l + 2) * DW]; }
      f32x4 Bc[4] = { Bn[0], Bn[1], Bn[2], Bn[3] };
      if (l + 1 < SC_CL) {
        const f32x4* bn = (const f32x4*)(bP + (l + 1) * 32);
#pragma unroll
        for (int q = 0; q < 4; ++q) Bn[q] = bn[q];
      }
      float dt0 = bflo(dc), dt1 = bfhi(dc);
      float x0 = bflo(xc),  x1 = bfhi(xc);
      float dtx0 = dt0 * x0, dtx1 = dt1 * x1;
#pragma unroll
      for (int s = 0; s < DSTATE; ++s) {
        float bs = Bc[s >> 2][s & 3];
        float dA0 = fmaf(A0[s], dt0, 1.f);
        float dA1 = fmaf(A1[s], dt1, 1.f);
        P0[s] *= dA0; P1[s] *= dA1;
        H0[s] = fmaf(H0[s], dA0, bs * dtx0);
        H1[s] = fmaf(H1[s], dA1, bs * dtx1);
      }
    }
  }
  {
    float* p = cP + (ck * 16 + dl) * 33;
    float* h = cH + (ck * 16 + dl) * 33;
#pragma unroll
    for (int s = 0; s < DSTATE; ++s) {
      p[s] = P0[s]; p[16 + s] = P1[s];
      h[s] = H0[s]; h[16 + s] = H1[s];
    }
  }
  __syncthreads();

  {
    const int s2 = tid & 15, dd = tid >> 4;
    const int idx = (dd & 1) * 16 + s2;
    float* pbase = cP + (dd >> 1) * 33 + idx;
    float* hbase = cH + (dd >> 1) * 33 + idx;
    float h = 0.f;
    for (int c = 0; c < SC_NC; ++c) {
      float p = pbase[c * 16 * 33], hh = hbase[c * 16 * 33];
      pbase[c * 16 * 33] = h;
      h = fmaf(p, h, hh);
    }
  }
  __syncthreads();

  float h0[DSTATE], h1[DSTATE];
  {
    const float* p = cP + (ck * 16 + dl) * 33;
#pragma unroll
    for (int s = 0; s < DSTATE; ++s) { h0[s] = p[s]; h1[s] = p[16 + s]; }
  }
  const float Dv0 = Dp[d0], Dv1 = Dp[d0 + 1];
  u32* yP = (u32*)(yg + (size_t)r0 * DINNER + d0);
  {
    u32 dq0 = dP[0], xq0 = xP[0], zq0 = zP[0];
    u32 dq1 = dP[DW], xq1 = xP[DW], zq1 = zP[ZW];
    f32x4 Bn[4], Cn[4];
#pragma unroll
    for (int q = 0; q < 4; ++q) { Bn[q] = ((const f32x4*)bP)[q]; Cn[q] = ((const f32x4*)bP)[q + 4]; }
    for (int l = 0; l < SC_CL; ++l) {
      const u32 dc = dq0, xc = xq0, zc = zq0;
      dq0 = dq1; xq0 = xq1; zq0 = zq1;
      if (l + 2 < SC_CL) { dq1 = dP[(l + 2) * DW]; xq1 = xP[(l + 2) * DW]; zq1 = zP[(l + 2) * ZW]; }
      f32x4 Bc[4] = { Bn[0], Bn[1], Bn[2], Bn[3] };
      f32x4 Cc[4] = { Cn[0], Cn[1], Cn[2], Cn[3] };
      if (l + 1 < SC_CL) {
        const f32x4* bn = (const f32x4*)(bP + (l + 1) * 32);
#pragma unroll
        for (int q = 0; q < 4; ++q) { Bn[q] = bn[q]; Cn[q] = bn[q + 4]; }
      }
      float dt0 = bflo(dc), dt1 = bfhi(dc);
      float x0 = bflo(xc),  x1 = bfhi(xc);
      float dtx0 = dt0 * x0, dtx1 = dt1 * x1;
      float yp0 = 0.f, yp1 = 0.f;
#pragma unroll
      for (int s = 0; s < DSTATE; ++s) {
        float bs = Bc[s >> 2][s & 3];
        float cs = Cc[s >> 2][s & 3];
        float dA0 = fmaf(A0[s], dt0, 1.f);
        float dA1 = fmaf(A1[s], dt1, 1.f);
        h0[s] = fmaf(h0[s], dA0, bs * dtx0);
        h1[s] = fmaf(h1[s], dA1, bs * dtx1);
        yp0 = fmaf(h0[s], cs, yp0);
        yp1 = fmaf(h1[s], cs, yp1);
      }
      float z0 = bflo(zc), z1 = bfhi(zc);
      float y0 = (yp0 + Dv0 * x0) * (z0 / (1.f + __expf(-z0)));
      float y1 = (yp1 + Dv1 * x1) * (z1 / (1.f + __expf(-z1)));
      yP[l * DW] = (u32)f2bf(y0) | ((u32)f2bf(y1) << 16);
    }
  }
}

extern "C" void kernel_launch(void* const* d_in, const int* in_sizes, int n_in,
                              void* d_out, int out_size, void* d_ws, size_t ws_size,
                              hipStream_t stream) {
  const float* x       = (const float*)d_in[0];
  const float* W_in    = (const float*)d_in[1];
  const float* conv_w  = (const float*)d_in[2];
  const float* conv_b  = (const float*)d_in[3];
  const float* W_xproj = (const float*)d_in[4];
  const float* W_dt    = (const float*)d_in[5];
  const float* b_dt    = (const float*)d_in[6];
  const float* A_log   = (const float*)d_in[7];
  const float* D_param = (const float*)d_in[8];
  const float* W_out   = (const float*)d_in[9];
  float* out = (float*)d_out;

  char* ws = (char*)d_ws;
  const size_t MB = 1ull << 20;
  u16*   x_bf  = (u16*)(ws);              // 16 MB   [dead after GEMM1]
  u16*   WinT  = (u16*)(ws + 16 * MB);    //  8 MB   [dead after GEMM1]
  u16*   WdtT  = (u16*)(ws + 24 * MB);    //  8 MB   [dead after GEMM2]
  u16*   xz_bf = (u16*)(ws + 32 * MB);    // 64 MB   [live through scan]
  u16*   xs_bf = (u16*)(ws + 96 * MB);    // 32 MB   [live through scan]
  u16*   delta = (u16*)(ws + 128 * MB);   // 32 MB (bf16)
  float* xpj   = (float*)(ws + 192 * MB); //  1 MB
  u16*   WoutT = (u16*)(ws + 193 * MB);   //  4 MB
  u16*   yg    = (u16*)(ws);              // 32 MB, aliases x_bf/WinT/WdtT (dead by then)

  hipFuncSetAttribute((const void*)gemm8p<0, 256>, hipFuncAttributeMaxDynamicSharedMemorySize, 131072);
  hipFuncSetAttribute((const void*)gemm8p<1, 256>, hipFuncAttributeMaxDynamicSharedMemorySize, 131072);
  hipFuncSetAttribute((const void*)gemm8p<2, 128>, hipFuncAttributeMaxDynamicSharedMemorySize, 98304);
  hipFuncSetAttribute((const void*)scan_v3, hipFuncAttributeMaxDynamicSharedMemorySize, SC_LDS);

  dim3 tb(32, 8);

  // 1) casts / weight transposes
  cast_f32_bf16<<<(ROWS * DMODEL / 4 + 255) / 256, 256, 0, stream>>>(x, x_bf, ROWS * DMODEL / 4);
  transpose_cast<<<dim3((2 * DINNER) / 32, DMODEL / 32), tb, 0, stream>>>(W_in, WinT, DMODEL, 2 * DINNER);
  transpose_cast<<<dim3(DINNER / 32, DINNER / 32), tb, 0, stream>>>(W_dt, WdtT, DINNER, DINNER);
  transpose_cast<<<dim3(DMODEL / 32, DINNER / 32), tb, 0, stream>>>(W_out, WoutT, DINNER, DMODEL);

  // 2) xz = x @ W_in   (8192 x 4096, K=1024) -> bf16. grid 512, XCD tile 8x8
  gemm8p<0, 256><<<512, 512, 131072, stream>>>(x_bf, WinT, xz_bf, nullptr,
                                               ROWS, 2 * DINNER, DMODEL, 16, 8, 8);

  // 3) xs = silu(causal_conv(xc) + conv_b) -> bf16 (4 d per thread)
  conv_silu4<<<(ROWS * DINNER / 4) / 256, 256, 0, stream>>>(
      xz_bf, conv_w, conv_b, xs_bf, ROWS * DINNER / 4);

  // 4) delta = softplus(xs @ W_dt + b_dt) (8192 x 2048, K=2048) -> bf16. grid 256, XCD tile 4x8
  gemm8p<1, 256><<<256, 512, 131072, stream>>>(xs_bf, WdtT, delta, b_dt,
                                               ROWS, DINNER, DINNER, 8, 4, 8);

  // 5) [Bs|Cs] = xs @ W_xproj   (8192 x 32) -> f32
  xproj_kernel<<<ROWS, 256, 0, stream>>>(xs_bf, W_xproj, xpj);

  // 6) chunked selective scan v3 + D-skip + silu(z) gate -> yg bf16
  scan_v3<<<BATCH * (DINNER / 32), 512, SC_LDS, stream>>>(
      delta, xs_bf, xpj, xz_bf, A_log, D_param, yg);

  // 7) out = yg @ W_out  (8192 x 1024, K=2048) -> f32. BN=128, grid 256, XCD tile 4x8
  gemm8p<2, 128><<<256, 512, 98304, stream>>>(yg, WoutT, out, nullptr,
                                              ROWS, DMODEL, DINNER, 8, 4, 8);
}

// Round 13
// 473.553 us; speedup vs baseline: 1.2645x; 1.2645x over previous
//
#include <hip/hip_runtime.h>

#define AS1 __attribute__((address_space(1)))
#define AS3 __attribute__((address_space(3)))

typedef unsigned short u16;
typedef unsigned int u32;
typedef __attribute__((ext_vector_type(8))) __bf16 bf16x8;
typedef __attribute__((ext_vector_type(8))) unsigned short u16x8;
typedef __attribute__((ext_vector_type(4))) float f32x4;

// Problem constants
#define BATCH   4
#define SEQLEN  2048
#define DMODEL  1024
#define DINNER  2048
#define DSTATE  16
#define ROWS    (BATCH * SEQLEN)   // 8192

__device__ __forceinline__ u16 f2bf(float f) {
  union { float f; unsigned u; } v; v.f = f;
  unsigned u = v.u;
  return (u16)((u + 0x7fffu + ((u >> 16) & 1u)) >> 16);   // RNE
}
__device__ __forceinline__ float bf2f(u16 s) {
  union { unsigned u; float f; } v; v.u = ((unsigned)s) << 16;
  return v.f;
}
__device__ __forceinline__ float bflo(u32 p) { union { unsigned u; float f; } v; v.u = p << 16; return v.f; }
__device__ __forceinline__ float bfhi(u32 p) { union { unsigned u; float f; } v; v.u = p & 0xffff0000u; return v.f; }

// asm ds_read_b128 with compile-time offset; address is a 32-bit LDS byte address.
template<int IMM>
__device__ __forceinline__ bf16x8 dsr(unsigned addr) {
  bf16x8 r;
  asm volatile("ds_read_b128 %0, %1 offset:%2" : "=&v"(r) : "v"(addr), "i"(IMM));
  return r;
}
__device__ __forceinline__ unsigned lds_addr(const u16* p) {
  return (unsigned)(size_t)(const AS3 u16*)p;
}

// ---------------- cast f32 -> bf16 (4 elems/thread) ----------------
__global__ void cast_f32_bf16(const float* __restrict__ in, u16* __restrict__ out, int n4) {
  int i = blockIdx.x * blockDim.x + threadIdx.x;
  if (i >= n4) return;
  float4 v = ((const float4*)in)[i];
  ushort4 o;
  o.x = f2bf(v.x); o.y = f2bf(v.y); o.z = f2bf(v.z); o.w = f2bf(v.w);
  ((ushort4*)out)[i] = o;
}

// ---------------- transpose + cast: in f32 (R x C) -> out bf16 (C x R) ----------------
__global__ void transpose_cast(const float* __restrict__ in, u16* __restrict__ out, int R, int C) {
  __shared__ float tile[32][33];
  int x  = blockIdx.x * 32 + threadIdx.x;
  int y0 = blockIdx.y * 32;
#pragma unroll
  for (int j = 0; j < 32; j += 8)
    tile[threadIdx.y + j][threadIdx.x] = in[(size_t)(y0 + threadIdx.y + j) * C + x];
  __syncthreads();
  int xo  = blockIdx.y * 32 + threadIdx.x;
  int yo0 = blockIdx.x * 32;
#pragma unroll
  for (int j = 0; j < 32; j += 8)
    out[(size_t)(yo0 + threadIdx.y + j) * R + xo] = f2bf(tile[threadIdx.x][threadIdx.y + j]);
}

// ---------------- 256xBN 8-phase bf16 MFMA GEMM (R6 version — best measured) ----------------
// Fine-interleaved phases: {ds_reads, stage one 2-chunk group, barrier, lgkm(0)+
// sched_barrier (rule #18), setprio(1), MFMA cluster, setprio(0), [counted vmcnt
// at q2 phases — never 0 mid-loop], barrier}. T2 swizzle (pre-swizzled global
// source + swizzled asm ds_read, linear LDS dest) -> 0 bank conflicts. 2D XCD
// supertiles for L2 locality. 512 thr = 8 waves (2M x 4N), BK=64, 128 KB dbuf.
// EPI: 0 = store bf16, 1 = softplus(v + bias[col]) -> bf16, 2 = store f32
template<int EPI, int BN_>
__launch_bounds__(512, 1)
__global__ void gemm8p(const u16* __restrict__ A, const u16* __restrict__ Bt,
                       void* __restrict__ outp, const float* __restrict__ bias,
                       int M, int N, int K, int gn, int rr, int cc) {
  constexpr int NF   = BN_ / 64;
  constexpr int BCH  = BN_ / 64;
  constexpr int ASZ  = 256 * 64;
  constexpr int BSZ  = BN_ * 64;
  constexpr int BUFS = ASZ + BSZ;
  extern __shared__ u16 lds[];

  const int xcd = blockIdx.x & 7, kb = blockIdx.x >> 3;
  const int tpr = gn / cc;
  const int bm  = (xcd / tpr) * rr + kb / cc;
  const int bn  = (xcd % tpr) * cc + kb % cc;

  const int tid  = threadIdx.x;
  const int wave = tid >> 6, lane = tid & 63;
  const int wm = wave >> 2, wn = wave & 3;
  const int llo = lane & 15, lhi = lane >> 4;
  const size_t bm0 = (size_t)bm * 256, bn0 = (size_t)bn * BN_;
  const int NT = K >> 6;

  const u16* gA[4];
#pragma unroll
  for (int ch = 0; ch < 4; ++ch) {
    int row  = ch * 64 + (tid >> 3);
    int scol = ((tid & 7) ^ (row & 7)) << 3;
    gA[ch] = A + (bm0 + row) * (size_t)K + scol;
  }
  const u16* gB[BCH];
#pragma unroll
  for (int ch = 0; ch < BCH; ++ch) {
    int row  = ch * 64 + (tid >> 3);
    int scol = ((tid & 7) ^ (row & 7)) << 3;
    gB[ch] = Bt + (bn0 + row) * (size_t)K + scol;
  }

  unsigned aA[2][2], aB[2][2];
  {
    const unsigned base0 = lds_addr(lds);
    const unsigned rowA = (unsigned)(wm * 128 + llo) * 128u;
    const unsigned rowB = (unsigned)(wn * (NF * 16) + llo) * 128u;
    const unsigned msk = (unsigned)((llo & 7) << 4);
#pragma unroll
    for (int bf = 0; bf < 2; ++bf)
#pragma unroll
      for (int kk = 0; kk < 2; ++kk) {
        unsigned colk = ((unsigned)(kk * 64 + lhi * 16)) ^ msk;
        aA[bf][kk] = base0 + (unsigned)bf * (BUFS * 2) + rowA + colk;
        aB[bf][kk] = base0 + (unsigned)bf * (BUFS * 2) + (ASZ * 2) + rowB + colk;
      }
  }

#define SGA(t, bsel, ch) __builtin_amdgcn_global_load_lds(                       \
    (const AS1 void*)(gA[ch] + ((size_t)(t) << 6)),                              \
    (AS3 void*)(lds + (bsel) * BUFS + (ch) * 4096 + wave * 512), 16, 0, 0)
#define SGB(t, bsel, ch) __builtin_amdgcn_global_load_lds(                       \
    (const AS1 void*)(gB[ch] + ((size_t)(t) << 6)),                              \
    (AS3 void*)(lds + (bsel) * BUFS + ASZ + (ch) * 4096 + wave * 512), 16, 0, 0)

  f32x4 acc[8][NF] = {};
  bf16x8 bfr[2][4];

#define PHASE(BUF, MH, KK, RDB, STG, WC)                                         \
  {                                                                              \
    bf16x8 af[4];                                                                \
    af[0] = dsr<(MH) * 8192 + 0>(aA[BUF][KK]);                                   \
    af[1] = dsr<(MH) * 8192 + 2048>(aA[BUF][KK]);                                \
    af[2] = dsr<(MH) * 8192 + 4096>(aA[BUF][KK]);                                \
    af[3] = dsr<(MH) * 8192 + 6144>(aA[BUF][KK]);                                \
    if (RDB) {                                                                   \
      bfr[KK][0] = dsr<0>(aB[BUF][KK]);                                          \
      bfr[KK][1] = dsr<2048>(aB[BUF][KK]);                                       \
      if (NF == 4) {                                                             \
        bfr[KK][2] = dsr<4096>(aB[BUF][KK]);                                     \
        bfr[KK][3] = dsr<6144>(aB[BUF][KK]);                                     \
      }                                                                          \
    }                                                                            \
    STG;                                                                         \
    asm volatile("s_barrier" ::: "memory");                                      \
    asm volatile("s_waitcnt lgkmcnt(0)" ::: "memory");                           \
    __builtin_amdgcn_sched_barrier(0);                                           \
    __builtin_amdgcn_s_setprio(1);                                               \
    _Pragma("unroll") for (int m = 0; m < 4; ++m)                                \
      _Pragma("unroll") for (int n = 0; n < NF; ++n)                             \
        acc[(MH) * 4 + m][n] = __builtin_amdgcn_mfma_f32_16x16x32_bf16(          \
            af[m], bfr[KK][n], acc[(MH) * 4 + m][n], 0, 0, 0);                   \
    __builtin_amdgcn_s_setprio(0);                                               \
    WC;                                                                          \
    asm volatile("s_barrier" ::: "memory");                                      \
  }

  SGA(0, 0, 0); SGA(0, 0, 2); SGB(0, 0, 0); SGB(0, 0, 1);
  if (BCH == 4) { SGB(0, 0, 2); SGB(0, 0, 3); }
  SGA(0, 0, 1); SGA(0, 0, 3);
  SGA(1, 1, 0); SGA(1, 1, 2); SGB(1, 1, 0); SGB(1, 1, 1);
  asm volatile("s_waitcnt vmcnt(4)" ::: "memory");
  asm volatile("s_barrier" ::: "memory");

  for (int u = 0; u < NT; u += 2) {
    const int v = u + 1;
    PHASE(0, 0, 0, true,
          ({ if (BCH == 4) { SGB(v, 1, 2); SGB(v, 1, 3); } else { SGA(v, 1, 1); SGA(v, 1, 3); } }),
          ((void)0));
    PHASE(0, 0, 1, true,
          ({ if (BCH == 4) { SGA(v, 1, 1); SGA(v, 1, 3); } }),
          ((void)0));
    PHASE(0, 1, 0, false,
          ({ if (u + 2 < NT) { SGA(u + 2, 0, 0); SGA(u + 2, 0, 2); } }),
          ((void)0));
    PHASE(0, 1, 1, false,
          ({ if (u + 2 < NT) { SGB(u + 2, 0, 0); SGB(u + 2, 0, 1); } }),
          ({ if (u + 2 < NT) asm volatile("s_waitcnt vmcnt(4)" ::: "memory");
             else            asm volatile("s_waitcnt vmcnt(0)" ::: "memory"); }));
    PHASE(1, 0, 0, true,
          ({ if (u + 2 < NT) { if (BCH == 4) { SGB(u + 2, 0, 2); SGB(u + 2, 0, 3); }
                               else          { SGA(u + 2, 0, 1); SGA(u + 2, 0, 3); } } }),
          ((void)0));
    PHASE(1, 0, 1, true,
          ({ if (u + 2 < NT && BCH == 4) { SGA(u + 2, 0, 1); SGA(u + 2, 0, 3); } }),
          ((void)0));
    PHASE(1, 1, 0, false,
          ({ if (v + 2 < NT) { SGA(v + 2, 1, 0); SGA(v + 2, 1, 2); } }),
          ((void)0));
    PHASE(1, 1, 1, false,
          ({ if (v + 2 < NT) { SGB(v + 2, 1, 0); SGB(v + 2, 1, 1); } }),
          ({ if (v + 2 < NT) asm volatile("s_waitcnt vmcnt(4)" ::: "memory");
             else            asm volatile("s_waitcnt vmcnt(0)" ::: "memory"); }));
  }
#undef PHASE
#undef SGA
#undef SGB

#pragma unroll
  for (int am = 0; am < 8; ++am) {
    const int mh = am >> 2, m = am & 3;
    const int rowb = (int)bm0 + wm * 128 + mh * 64 + m * 16 + lhi * 4;
#pragma unroll
    for (int n = 0; n < NF; ++n) {
      const int col = (int)bn0 + wn * (16 * NF) + n * 16 + llo;
#pragma unroll
      for (int r = 0; r < 4; ++r) {
        float v = acc[am][n][r];
        size_t idx = (size_t)(rowb + r) * N + col;
        if (EPI == 0) {
          ((u16*)outp)[idx] = f2bf(v);
        } else if (EPI == 1) {
          float xb = v + bias[col];
          float sp = (xb > 20.f) ? xb : log1pf(__expf(xb));  // softplus
          ((u16*)outp)[idx] = f2bf(sp);
        } else {
          ((float*)outp)[idx] = v;
        }
      }
    }
  }
}

// ---------------- causal depthwise conv (K=4) + SiLU, 4 d per thread ----------------
__global__ void conv_silu4(const u16* __restrict__ xz, const float* __restrict__ w,
                           const float* __restrict__ cb, u16* __restrict__ xs, int total4) {
  int idx = blockIdx.x * 256 + threadIdx.x;
  if (idx >= total4) return;
  int d4 = idx & (DINNER / 4 - 1);
  int l  = (idx >> 9) & (SEQLEN - 1);
  int b  = idx >> 20;
  int d  = d4 * 4;
  float4 wv[4];
#pragma unroll
  for (int j = 0; j < 4; ++j) wv[j] = ((const float4*)w)[d + j];
  float4 bias = *(const float4*)(cb + d);
  float acc[4] = { bias.x, bias.y, bias.z, bias.w };
#pragma unroll
  for (int k = 0; k < 4; ++k) {
    int li = l - 3 + k;
    if (li >= 0) {
      ushort4 xv = *(const ushort4*)(xz + (size_t)(b * SEQLEN + li) * (2 * DINNER) + d);
      acc[0] = fmaf((&wv[0].x)[k], bf2f(xv.x), acc[0]);
      acc[1] = fmaf((&wv[1].x)[k], bf2f(xv.y), acc[1]);
      acc[2] = fmaf((&wv[2].x)[k], bf2f(xv.z), acc[2]);
      acc[3] = fmaf((&wv[3].x)[k], bf2f(xv.w), acc[3]);
    }
  }
  ushort4 o;
  o.x = f2bf(acc[0] / (1.f + __expf(-acc[0])));
  o.y = f2bf(acc[1] / (1.f + __expf(-acc[1])));
  o.z = f2bf(acc[2] / (1.f + __expf(-acc[2])));
  o.w = f2bf(acc[3] / (1.f + __expf(-acc[3])));
  *(ushort4*)(xs + (size_t)idx * 4) = o;
}

// ---------------- x-projection: xproj(ROWS x 32) = xs(ROWS x 2048) @ Wx(2048 x 32) ----------------
__global__ void xproj_kernel(const u16* __restrict__ xs, const float* __restrict__ Wx,
                             float* __restrict__ outp) {
  __shared__ float part[256];
  int row = blockIdx.x;
  int tid = threadIdx.x;
  int c = tid & 31, kp = tid >> 5;
  const u16* xr = xs + (size_t)row * DINNER + kp * 256;
  const float* wp = Wx + (size_t)(kp * 256) * 32 + c;
  float acc = 0.f;
#pragma unroll 4
  for (int kk = 0; kk < 32; ++kk) {
    u16x8 xv = *(const u16x8*)(const void*)(xr + kk * 8);
#pragma unroll
    for (int j = 0; j < 8; ++j)
      acc = fmaf(bf2f(xv[j]), wp[(kk * 8 + j) * 32], acc);
  }
  part[tid] = acc;
  __syncthreads();
  if (tid < 32) {
    float s = 0.f;
#pragma unroll
    for (int p = 0; p < 8; ++p) s += part[p * 32 + tid];
    outp[(size_t)row * 32 + tid] = s;
  }
}

// ---------------- chunked selective scan v3 (best measured) ----------------
#define SC_NC 32                // chunks
#define SC_CL 64                // steps per chunk
#define SC_LDS (2 * SC_NC * 16 * 33 * 4)   // 135168 B

__launch_bounds__(512, 1)
__global__ void scan_v3(const u16* __restrict__ delta, const u16* __restrict__ xs,
                        const float* __restrict__ xproj, const u16* __restrict__ xz,
                        const float* __restrict__ A_log, const float* __restrict__ Dp,
                        u16* __restrict__ yg) {
  extern __shared__ float smem[];
  float* cP = smem;
  float* cH = smem + SC_NC * 16 * 33;
  const int tid = threadIdx.x;
  const int dl = tid & 15, ck = tid >> 4;
  const int b = blockIdx.x >> 6, dblk = blockIdx.x & 63;
  const int d0 = dblk * 32 + dl * 2;
  const int r0 = b * SEQLEN + ck * SC_CL;

  float A0[DSTATE], A1[DSTATE];
  {
    const f32x4* ap0 = (const f32x4*)(A_log + (size_t)d0 * DSTATE);
    const f32x4* ap1 = (const f32x4*)(A_log + (size_t)(d0 + 1) * DSTATE);
#pragma unroll
    for (int q = 0; q < 4; ++q) {
      f32x4 a0 = ap0[q], a1 = ap1[q];
#pragma unroll
      for (int j = 0; j < 4; ++j) { A0[q * 4 + j] = -__expf(a0[j]); A1[q * 4 + j] = -__expf(a1[j]); }
    }
  }

  const u32* dP = (const u32*)(delta + (size_t)r0 * DINNER + d0);
  const u32* xP = (const u32*)(xs    + (size_t)r0 * DINNER + d0);
  const u32* zP = (const u32*)(xz + (size_t)r0 * (2 * DINNER) + DINNER + d0);
  const float* bP = xproj + (size_t)r0 * 32;
  const int DW = DINNER / 2;
  const int ZW = DINNER;

  float P0[DSTATE], P1[DSTATE], H0[DSTATE], H1[DSTATE];
#pragma unroll
  for (int s = 0; s < DSTATE; ++s) { P0[s] = P1[s] = 1.f; H0[s] = H1[s] = 0.f; }
  {
    u32 dq0 = dP[0], xq0 = xP[0];
    u32 dq1 = dP[DW], xq1 = xP[DW];
    f32x4 Bn[4];
#pragma unroll
    for (int q = 0; q < 4; ++q) Bn[q] = ((const f32x4*)bP)[q];
    for (int l = 0; l < SC_CL; ++l) {
      const u32 dc = dq0, xc = xq0;
      dq0 = dq1; xq0 = xq1;
      if (l + 2 < SC_CL) { dq1 = dP[(l + 2) * DW]; xq1 = xP[(l + 2) * DW]; }
      f32x4 Bc[4] = { Bn[0], Bn[1], Bn[2], Bn[3] };
      if (l + 1 < SC_CL) {
        const f32x4* bn = (const f32x4*)(bP + (l + 1) * 32);
#pragma unroll
        for (int q = 0; q < 4; ++q) Bn[q] = bn[q];
      }
      float dt0 = bflo(dc), dt1 = bfhi(dc);
      float x0 = bflo(xc),  x1 = bfhi(xc);
      float dtx0 = dt0 * x0, dtx1 = dt1 * x1;
#pragma unroll
      for (int s = 0; s < DSTATE; ++s) {
        float bs = Bc[s >> 2][s & 3];
        float dA0 = fmaf(A0[s], dt0, 1.f);
        float dA1 = fmaf(A1[s], dt1, 1.f);
        P0[s] *= dA0; P1[s] *= dA1;
        H0[s] = fmaf(H0[s], dA0, bs * dtx0);
        H1[s] = fmaf(H1[s], dA1, bs * dtx1);
      }
    }
  }
  {
    float* p = cP + (ck * 16 + dl) * 33;
    float* h = cH + (ck * 16 + dl) * 33;
#pragma unroll
    for (int s = 0; s < DSTATE; ++s) {
      p[s] = P0[s]; p[16 + s] = P1[s];
      h[s] = H0[s]; h[16 + s] = H1[s];
    }
  }
  __syncthreads();

  {
    const int s2 = tid & 15, dd = tid >> 4;
    const int idx = (dd & 1) * 16 + s2;
    float* pbase = cP + (dd >> 1) * 33 + idx;
    float* hbase = cH + (dd >> 1) * 33 + idx;
    float h = 0.f;
    for (int c = 0; c < SC_NC; ++c) {
      float p = pbase[c * 16 * 33], hh = hbase[c * 16 * 33];
      pbase[c * 16 * 33] = h;
      h = fmaf(p, h, hh);
    }
  }
  __syncthreads();

  float h0[DSTATE], h1[DSTATE];
  {
    const float* p = cP + (ck * 16 + dl) * 33;
#pragma unroll
    for (int s = 0; s < DSTATE; ++s) { h0[s] = p[s]; h1[s] = p[16 + s]; }
  }
  const float Dv0 = Dp[d0], Dv1 = Dp[d0 + 1];
  u32* yP = (u32*)(yg + (size_t)r0 * DINNER + d0);
  {
    u32 dq0 = dP[0], xq0 = xP[0], zq0 = zP[0];
    u32 dq1 = dP[DW], xq1 = xP[DW], zq1 = zP[ZW];
    f32x4 Bn[4], Cn[4];
#pragma unroll
    for (int q = 0; q < 4; ++q) { Bn[q] = ((const f32x4*)bP)[q]; Cn[q] = ((const f32x4*)bP)[q + 4]; }
    for (int l = 0; l < SC_CL; ++l) {
      const u32 dc = dq0, xc = xq0, zc = zq0;
      dq0 = dq1; xq0 = xq1; zq0 = zq1;
      if (l + 2 < SC_CL) { dq1 = dP[(l + 2) * DW]; xq1 = xP[(l + 2) * DW]; zq1 = zP[(l + 2) * ZW]; }
      f32x4 Bc[4] = { Bn[0], Bn[1], Bn[2], Bn[3] };
      f32x4 Cc[4] = { Cn[0], Cn[1], Cn[2], Cn[3] };
      if (l + 1 < SC_CL) {
        const f32x4* bn = (const f32x4*)(bP + (l + 1) * 32);
#pragma unroll
        for (int q = 0; q < 4; ++q) { Bn[q] = bn[q]; Cn[q] = bn[q + 4]; }
      }
      float dt0 = bflo(dc), dt1 = bfhi(dc);
      float x0 = bflo(xc),  x1 = bfhi(xc);
      float dtx0 = dt0 * x0, dtx1 = dt1 * x1;
      float yp0 = 0.f, yp1 = 0.f;
#pragma unroll
      for (int s = 0; s < DSTATE; ++s) {
        float bs = Bc[s >> 2][s & 3];
        float cs = Cc[s >> 2][s & 3];
        float dA0 = fmaf(A0[s], dt0, 1.f);
        float dA1 = fmaf(A1[s], dt1, 1.f);
        h0[s] = fmaf(h0[s], dA0, bs * dtx0);
        h1[s] = fmaf(h1[s], dA1, bs * dtx1);
        yp0 = fmaf(h0[s], cs, yp0);
        yp1 = fmaf(h1[s], cs, yp1);
      }
      float z0 = bflo(zc), z1 = bfhi(zc);
      float y0 = (yp0 + Dv0 * x0) * (z0 / (1.f + __expf(-z0)));
      float y1 = (yp1 + Dv1 * x1) * (z1 / (1.f + __expf(-z1)));
      yP[l * DW] = (u32)f2bf(y0) | ((u32)f2bf(y1) << 16);
    }
  }
}

extern "C" void kernel_launch(void* const* d_in, const int* in_sizes, int n_in,
                              void* d_out, int out_size, void* d_ws, size_t ws_size,
                              hipStream_t stream) {
  const float* x       = (const float*)d_in[0];
  const float* W_in    = (const float*)d_in[1];
  const float* conv_w  = (const float*)d_in[2];
  const float* conv_b  = (const float*)d_in[3];
  const float* W_xproj = (const float*)d_in[4];
  const float* W_dt    = (const float*)d_in[5];
  const float* b_dt    = (const float*)d_in[6];
  const float* A_log   = (const float*)d_in[7];
  const float* D_param = (const float*)d_in[8];
  const float* W_out   = (const float*)d_in[9];
  float* out = (float*)d_out;

  char* ws = (char*)d_ws;
  const size_t MB = 1ull << 20;
  u16*   x_bf  = (u16*)(ws);              // 16 MB   [dead after GEMM1]
  u16*   WinT  = (u16*)(ws + 16 * MB);    //  8 MB   [dead after GEMM1]
  u16*   WdtT  = (u16*)(ws + 24 * MB);    //  8 MB   [dead after GEMM2]
  u16*   xz_bf = (u16*)(ws + 32 * MB);    // 64 MB   [live through scan]
  u16*   xs_bf = (u16*)(ws + 96 * MB);    // 32 MB   [live through scan]
  u16*   delta = (u16*)(ws + 128 * MB);   // 32 MB (bf16)
  float* xpj   = (float*)(ws + 192 * MB); //  1 MB
  u16*   WoutT = (u16*)(ws + 193 * MB);   //  4 MB
  u16*   yg    = (u16*)(ws);              // 32 MB, aliases x_bf/WinT/WdtT (dead by then)

  hipFuncSetAttribute((const void*)gemm8p<0, 256>, hipFuncAttributeMaxDynamicSharedMemorySize, 131072);
  hipFuncSetAttribute((const void*)gemm8p<1, 256>, hipFuncAttributeMaxDynamicSharedMemorySize, 131072);
  hipFuncSetAttribute((const void*)gemm8p<2, 128>, hipFuncAttributeMaxDynamicSharedMemorySize, 98304);
  hipFuncSetAttribute((const void*)scan_v3, hipFuncAttributeMaxDynamicSharedMemorySize, SC_LDS);

  dim3 tb(32, 8);

  // 1) casts / weight transposes
  cast_f32_bf16<<<(ROWS * DMODEL / 4 + 255) / 256, 256, 0, stream>>>(x, x_bf, ROWS * DMODEL / 4);
  transpose_cast<<<dim3((2 * DINNER) / 32, DMODEL / 32), tb, 0, stream>>>(W_in, WinT, DMODEL, 2 * DINNER);
  transpose_cast<<<dim3(DINNER / 32, DINNER / 32), tb, 0, stream>>>(W_dt, WdtT, DINNER, DINNER);
  transpose_cast<<<dim3(DMODEL / 32, DINNER / 32), tb, 0, stream>>>(W_out, WoutT, DINNER, DMODEL);

  // 2) xz = x @ W_in   (8192 x 4096, K=1024) -> bf16. grid 512, XCD tile 8x8
  gemm8p<0, 256><<<512, 512, 131072, stream>>>(x_bf, WinT, xz_bf, nullptr,
                                               ROWS, 2 * DINNER, DMODEL, 16, 8, 8);

  // 3) xs = silu(causal_conv(xc) + conv_b) -> bf16 (4 d per thread)
  conv_silu4<<<(ROWS * DINNER / 4) / 256, 256, 0, stream>>>(
      xz_bf, conv_w, conv_b, xs_bf, ROWS * DINNER / 4);

  // 4) delta = softplus(xs @ W_dt + b_dt) (8192 x 2048, K=2048) -> bf16. grid 256, XCD tile 4x8
  gemm8p<1, 256><<<256, 512, 131072, stream>>>(xs_bf, WdtT, delta, b_dt,
                                               ROWS, DINNER, DINNER, 8, 4, 8);

  // 5) [Bs|Cs] = xs @ W_xproj   (8192 x 32) -> f32
  xproj_kernel<<<ROWS, 256, 0, stream>>>(xs_bf, W_xproj, xpj);

  // 6) chunked selective scan v3 + D-skip + silu(z) gate -> yg bf16
  scan_v3<<<BATCH * (DINNER / 32), 512, SC_LDS, stream>>>(
      delta, xs_bf, xpj, xz_bf, A_log, D_param, yg);

  // 7) out = yg @ W_out  (8192 x 1024, K=2048) -> f32. BN=128, grid 256, XCD tile 4x8
  gemm8p<2, 128><<<256, 512, 98304, stream>>>(yg, WoutT, out, nullptr,
                                              ROWS, DMODEL, DINNER, 8, 4, 8);
}